// Round 4
// baseline (545.030 us; speedup 1.0000x reference)
//
#include <hip/hip_runtime.h>
#include <hip/hip_bf16.h>

// GlobalSLC: out = out_s + out_d
//   static : y1 = ws@x; y2 = 2ws@y1 - x; y3 = 2ws@y2 - y1
//   dynamic: collapses to 32x32 algebra (G = x^T x, W = G wp, H1 = W G, H2 = 2 W H1 - G)
//   out = x@(2ts0-td2) + xp@(G td1 + 2 H1 td2 + (2H2-G) td3) + y1@ts1 + y2@ts2 + y3@ts3
//
// R4: gemm1 reads ws with CONTIGUOUS 1KB-per-instruction loads (lane-along-K), converts
// to bf16, transposes to MFMA A-layout via a PER-WAVE swizzled LDS buffer (no barriers —
// each wave reads only rows it wrote; lgkmcnt handles the ordering). gemm2 keeps the
// fragment-ordered wsb stream but caps unrolling to avoid VGPR spill.

typedef __attribute__((ext_vector_type(8))) short short8;
typedef __attribute__((ext_vector_type(4))) float floatx4;

constexpr int NSPLIT = 16;      // split-K; 512 cols per split
constexpr int KT_PER = 8;       // 64-col k-tiles per split (gemm2)

__device__ inline unsigned short f2bf(float f) {
    union { float f; unsigned u; } v; v.f = f;
    unsigned r = v.u + 0x7FFFu + ((v.u >> 16) & 1u);   // RNE
    return (unsigned short)(r >> 16);
}

// ---------- prep: xp = x@wp, Gram partials, Vt = bf16(x^T) ----------
__global__ __launch_bounds__(256) void k_prep(const float* __restrict__ x,
                                              const float* __restrict__ wp,
                                              float* __restrict__ xp,
                                              float* __restrict__ Gpart,
                                              unsigned short* __restrict__ Vt) {
    __shared__ float sx[8192];
    __shared__ float swp[1024];
    __shared__ unsigned short st[32][264];
    const int t = threadIdx.x;
    const int n0 = blockIdx.x * 256;
    const floatx4* x4 = (const floatx4*)(x + (size_t)n0 * 32);
    floatx4* sx4 = (floatx4*)sx;
#pragma unroll
    for (int i = 0; i < 8; ++i) sx4[i * 256 + t] = x4[i * 256 + t];
    for (int i = t; i < 1024; i += 256) swp[i] = wp[i];
    __syncthreads();

    float row[32];
#pragma unroll
    for (int a = 0; a < 32; ++a) row[a] = sx[t * 32 + a];

    float* xpr = xp + (size_t)(n0 + t) * 32;
#pragma unroll
    for (int c = 0; c < 32; ++c) {
        float s = 0.f;
#pragma unroll
        for (int a = 0; a < 32; ++a) s += row[a] * swp[a * 32 + c];
        xpr[c] = s;
        st[c][t] = f2bf(row[c]);
    }

    const int a = t >> 3;
    const int b = 4 * (t & 7);
    float g0 = 0.f, g1 = 0.f, g2 = 0.f, g3 = 0.f;
    for (int i = 0; i < 256; ++i) {
        float va = sx[i * 32 + a];
        floatx4 vb = *(floatx4*)&sx[i * 32 + b];
        g0 += va * vb.x; g1 += va * vb.y; g2 += va * vb.z; g3 += va * vb.w;
    }
    floatx4 g = {g0, g1, g2, g3};
    *(floatx4*)&Gpart[(size_t)blockIdx.x * 1024 + (size_t)(a * 32 + b)] = g;

    __syncthreads();
#pragma unroll
    for (int c = 0; c < 32; ++c) Vt[(size_t)c * 8192 + n0 + t] = st[c][t];
}

// ---------- 32x32 coefficient algebra ----------
__global__ void k_coef(const float* __restrict__ Gpart, const float* __restrict__ wp,
                       const float* __restrict__ ts, const float* __restrict__ td,
                       float* __restrict__ Cx, float* __restrict__ Cxp) {
    __shared__ float G[1024], W[1024], H1[1024], H2[1024];
    __shared__ float swp[1024], td1[1024], td2[1024], td3[1024], ts0[1024];
    int t = threadIdx.x;
    int a = t >> 5, b = t & 31;
    float gs = 0.f;
    for (int p = 0; p < 32; ++p) gs += Gpart[p * 1024 + t];
    G[t] = gs; swp[t] = wp[t]; ts0[t] = ts[t];
    td1[t] = td[1024 + t]; td2[t] = td[2048 + t]; td3[t] = td[3072 + t];
    __syncthreads();
    float s = 0.f;
    for (int c = 0; c < 32; ++c) s += G[a * 32 + c] * swp[c * 32 + b];
    W[t] = s; __syncthreads();
    s = 0.f;
    for (int c = 0; c < 32; ++c) s += W[a * 32 + c] * G[c * 32 + b];
    H1[t] = s; __syncthreads();
    s = 0.f;
    for (int c = 0; c < 32; ++c) s += W[a * 32 + c] * H1[c * 32 + b];
    H2[t] = 2.f * s - G[t]; __syncthreads();
    s = 0.f;
    for (int c = 0; c < 32; ++c)
        s += G[a * 32 + c] * td1[c * 32 + b]
           + 2.f * H1[a * 32 + c] * td2[c * 32 + b]
           + (2.f * H2[a * 32 + c] - G[a * 32 + c]) * td3[c * 32 + b];
    Cxp[t] = s;
    Cx[t] = 2.f * ts0[t] - td2[t];
}

// ---------- pass 1: contiguous-load ws(fp32) @ V, fused fragment-ordered bf16 emit ----------
// grid (128, NSPLIT) x 256 = 4 waves. Wave wv owns rows bx*64+wv*16..+15, cols by*512..+511.
// Per 256-col step: 16 loads, each = ONE row's 1KB contiguous segment (lane-along-K);
// cvt->bf16; swizzled ds_write_b64 into the wave's PRIVATE 8KB LDS buffer; then 8 chunks of
// swizzled ds_read_b128 A-fragments -> 2 MFMAs each + contiguous fragment-ordered wsb store.
// No __syncthreads anywhere: no cross-wave LDS sharing.
__global__ __launch_bounds__(256) void k_gemm1(const float* __restrict__ A,
                                               unsigned short* __restrict__ wsb,
                                               const unsigned short* __restrict__ Vt,
                                               float* __restrict__ Ypart) {
    __shared__ unsigned short sbuf[4][16 * 256];   // per-wave 16 rows x 256 bf16 (8KB each)
    const int t = threadIdx.x;
    const int lane = t & 63;
    const int wv = t >> 6;
    const int l15 = lane & 15;
    const int l4 = lane >> 4;
    const int bx = blockIdx.x, by = blockIdx.y;
    const int k0 = by * 512;
    const int rowbase = bx * 64 + wv * 16;

    unsigned short* wout =
        wsb + (((size_t)(bx * NSPLIT + by) * 4096) + (size_t)wv * 64 + lane) * 8;
    const unsigned short* vb0 = Vt + (size_t)l15 * 8192 + k0 + l4 * 8;
    const unsigned short* vb1 = vb0 + (size_t)16 * 8192;
    unsigned short* mybuf = sbuf[wv];
    // swizzled write slot: chunk (lane>>1) ^ row, half (lane&1)
    const int wchunk = lane >> 1, whalf = lane & 1;

    floatx4 acc0 = {0.f, 0.f, 0.f, 0.f};
    floatx4 acc1 = {0.f, 0.f, 0.f, 0.f};

    for (int s = 0; s < 2; ++s) {
        const int ks = k0 + s * 256;
        // stage 16 rows: contiguous 1KB per instruction
#pragma unroll
        for (int r = 0; r < 16; ++r) {
            floatx4 f = *(const floatx4*)(A + (size_t)(rowbase + r) * 8192 + ks + lane * 4);
            ushort4 h;
            h.x = f2bf(f.x); h.y = f2bf(f.y); h.z = f2bf(f.z); h.w = f2bf(f.w);
            *(ushort4*)(mybuf + r * 256 + ((wchunk ^ r) * 8 + whalf * 4)) = h;
        }
        // consume: 8 k-chunks of 32 cols
#pragma unroll 4
        for (int kk = 0; kk < 8; ++kk) {
            short8 av = *(short8*)(mybuf + l15 * 256 + (((kk * 4 + l4) ^ l15) * 8));
            const int kof = s * 256 + kk * 32;
            short8 b0 = *(const short8*)(vb0 + kof);
            short8 b1 = *(const short8*)(vb1 + kof);
            *(short8*)(wout + (size_t)(s * 8 + kk) * 2048) = av;
            acc0 = __builtin_amdgcn_mfma_f32_16x16x32_bf16(av, b0, acc0, 0, 0, 0);
            acc1 = __builtin_amdgcn_mfma_f32_16x16x32_bf16(av, b1, acc1, 0, 0, 0);
        }
    }
    float* yp = Ypart + (size_t)by * 262144;
    const int row0 = bx * 64 + wv * 16 + l4 * 4;
#pragma unroll
    for (int r = 0; r < 4; ++r) {
        yp[(size_t)(row0 + r) * 32 + l15] = acc0[r];
        yp[(size_t)(row0 + r) * 32 + 16 + l15] = acc1[r];
    }
}

// ---------- passes 2,3: Ypart = wsb(bf16, fragment-ordered) @ V partials ----------
__global__ __launch_bounds__(256) void k_gemm2(const unsigned short* __restrict__ wsb,
                                               const unsigned short* __restrict__ Vt,
                                               float* __restrict__ Ypart) {
    const int t = threadIdx.x;
    const int lane = t & 63;
    const int wv = t >> 6;
    const int l15 = lane & 15;
    const int l4 = lane >> 4;
    const int bx = blockIdx.x, by = blockIdx.y;
    const int k0 = by * 512;

    const short8* win = (const short8*)wsb
        + ((size_t)(bx * NSPLIT + by) * 4096) + (size_t)wv * 64 + lane;
    const unsigned short* vb0 = Vt + (size_t)l15 * 8192 + k0 + l4 * 8;
    const unsigned short* vb1 = vb0 + (size_t)16 * 8192;

    floatx4 acc0 = {0.f, 0.f, 0.f, 0.f};
    floatx4 acc1 = {0.f, 0.f, 0.f, 0.f};

#pragma unroll 2
    for (int kt = 0; kt < KT_PER; ++kt) {
#pragma unroll
        for (int i = 0; i < 2; ++i) {
            const int kk = kt * 64 + i * 32;
            short8 av = win[(size_t)(kt * 2 + i) * 256];
            short8 b0 = *(const short8*)(vb0 + kk);
            short8 b1 = *(const short8*)(vb1 + kk);
            acc0 = __builtin_amdgcn_mfma_f32_16x16x32_bf16(av, b0, acc0, 0, 0, 0);
            acc1 = __builtin_amdgcn_mfma_f32_16x16x32_bf16(av, b1, acc1, 0, 0, 0);
        }
    }
    float* yp = Ypart + (size_t)by * 262144;
    const int row0 = bx * 64 + wv * 16 + l4 * 4;
#pragma unroll
    for (int r = 0; r < 4; ++r) {
        yp[(size_t)(row0 + r) * 32 + l15] = acc0[r];
        yp[(size_t)(row0 + r) * 32 + 16 + l15] = acc1[r];
    }
}

// ---------- reduce split-K partials + alpha/beta + emit y and bf16(y^T) ----------
__global__ __launch_bounds__(256) void k_trans(const float* __restrict__ Ypart,
                                               const float* __restrict__ prev,
                                               float alpha, float beta,
                                               float* __restrict__ y,
                                               unsigned short* __restrict__ Vt) {
    __shared__ unsigned short st[32][264];
    const int t = threadIdx.x;
    const int n0 = blockIdx.x * 256;
    const size_t base4 = (size_t)n0 * 8;
    floatx4 r[8];
#pragma unroll
    for (int j = 0; j < 8; ++j) r[j] = {0.f, 0.f, 0.f, 0.f};
    for (int p = 0; p < NSPLIT; ++p) {
        const floatx4* P4 = (const floatx4*)(Ypart + (size_t)p * 262144);
#pragma unroll
        for (int j = 0; j < 8; ++j) r[j] += P4[base4 + j * 256 + t];
    }
    const floatx4* prev4 = (const floatx4*)prev;
    floatx4* y4 = (floatx4*)y;
#pragma unroll
    for (int j = 0; j < 8; ++j) {
        floatx4 pv = prev4[base4 + j * 256 + t];
        floatx4 v;
        v.x = alpha * r[j].x + beta * pv.x;
        v.y = alpha * r[j].y + beta * pv.y;
        v.z = alpha * r[j].z + beta * pv.z;
        v.w = alpha * r[j].w + beta * pv.w;
        y4[base4 + j * 256 + t] = v;
        int q = j * 256 + t;
        int lr = q >> 3;
        int c4 = (q & 7) * 4;
        st[c4 + 0][lr] = f2bf(v.x);
        st[c4 + 1][lr] = f2bf(v.y);
        st[c4 + 2][lr] = f2bf(v.z);
        st[c4 + 3][lr] = f2bf(v.w);
    }
    __syncthreads();
#pragma unroll
    for (int c = 0; c < 32; ++c) Vt[(size_t)c * 8192 + n0 + t] = st[c][t];
}

// ---------- out = x@Cx + xp@Cxp + y1@ts1 + y2@ts2 + y3@ts3 ----------
__global__ void k_final(const float* __restrict__ x, const float* __restrict__ xp,
                        const float* __restrict__ y1, const float* __restrict__ y2,
                        const float* __restrict__ y3, const float* __restrict__ Cx,
                        const float* __restrict__ Cxp, const float* __restrict__ ts,
                        float* __restrict__ out) {
    __shared__ float m0[1024], m1[1024], m2[1024], m3[1024], m4[1024];
    int t = threadIdx.x;
    for (int i = t; i < 1024; i += 256) {
        m0[i] = Cx[i]; m1[i] = Cxp[i];
        m2[i] = ts[1024 + i]; m3[i] = ts[2048 + i]; m4[i] = ts[3072 + i];
    }
    __syncthreads();
    int g = blockIdx.x * 256 + t;
    int n = g >> 5, c = g & 31;
    const float* xr  = x  + (size_t)n * 32;
    const float* xpr = xp + (size_t)n * 32;
    const float* y1r = y1 + (size_t)n * 32;
    const float* y2r = y2 + (size_t)n * 32;
    const float* y3r = y3 + (size_t)n * 32;
    float s = 0.f;
#pragma unroll
    for (int a = 0; a < 32; ++a) {
        s += xr[a]  * m0[a * 32 + c]
           + xpr[a] * m1[a * 32 + c]
           + y1r[a] * m2[a * 32 + c]
           + y2r[a] * m3[a * 32 + c]
           + y3r[a] * m4[a * 32 + c];
    }
    out[g] = s;
}

extern "C" void kernel_launch(void* const* d_in, const int* in_sizes, int n_in,
                              void* d_out, int out_size, void* d_ws, size_t ws_size,
                              hipStream_t stream) {
    const float* x  = (const float*)d_in[0];   // 8192 x 32
    const float* ws = (const float*)d_in[1];   // 8192 x 8192
    const float* wp = (const float*)d_in[2];   // 32 x 32
    const float* ts = (const float*)d_in[3];   // 4 x 32 x 32
    const float* td = (const float*)d_in[4];   // 4 x 32 x 32
    float* out = (float*)d_out;

    char* w = (char*)d_ws;
    unsigned short* wsb = (unsigned short*)w;              // 128 MB, fragment-ordered bf16
    float* Ppart = (float*)(w + 134217728);                // NSPLIT x 8192 x 32 (16 MB)
    float* xp  = Ppart + (size_t)NSPLIT * 262144;
    float* y1  = xp + 262144;
    float* y2  = y1 + 262144;
    float* y3  = y2 + 262144;
    unsigned short* Vt = (unsigned short*)(y3 + 262144);   // 32 x 8192 bf16
    float* Gpart = (float*)(Vt + 262144);                  // 32 x 1024
    float* Cx  = Gpart + 32768;
    float* Cxp = Cx + 1024;

    dim3 gg(128, NSPLIT);
    k_prep<<<32, 256, 0, stream>>>(x, wp, xp, Gpart, Vt);
    k_coef<<<1, 1024, 0, stream>>>(Gpart, wp, ts, td, Cx, Cxp);
    // pass 1: y1 = ws @ x   (+ fused fragment-ordered bf16 emit)
    k_gemm1<<<gg, 256, 0, stream>>>(ws, wsb, Vt, Ppart);
    k_trans<<<32, 256, 0, stream>>>(Ppart, x, 1.0f, 0.0f, y1, Vt);
    // pass 2: y2 = 2 ws @ y1 - x
    k_gemm2<<<gg, 256, 0, stream>>>(wsb, Vt, Ppart);
    k_trans<<<32, 256, 0, stream>>>(Ppart, x, 2.0f, -1.0f, y2, Vt);
    // pass 3: y3 = 2 ws @ y2 - y1
    k_gemm2<<<gg, 256, 0, stream>>>(wsb, Vt, Ppart);
    k_trans<<<32, 256, 0, stream>>>(Ppart, y1, 2.0f, -1.0f, y3, Vt);

    k_final<<<1024, 256, 0, stream>>>(x, xp, y1, y2, y3, Cx, Cxp, ts, out);
}

// Round 5
// 517.192 us; speedup vs baseline: 1.0538x; 1.0538x over previous
//
#include <hip/hip_runtime.h>
#include <hip/hip_bf16.h>

// GlobalSLC: out = out_s + out_d
//   static : y1 = ws@x; y2 = 2ws@y1 - x; y3 = 2ws@y2 - y1
//   dynamic: collapses to 32x32 algebra (G = x^T x, W = G wp, H1 = W G, H2 = 2 W H1 - G)
//   out = x@(2ts0-td2) + xp@(G td1 + 2 H1 td2 + (2H2-G) td3) + y1@ts1 + y2@ts2 + y3@ts3
//
// R5: B operand stored PRE-FRAGMENTED in MFMA B-layout (Vb[kc][h][lane][8]) so B-loads are
// contiguous 1KB-per-instruction streams, same as the fragment-ordered A (wsb). No scattered
// global access remains in any gemm K-loop. gemm2: no LDS, no barriers, pure load->mfma.

typedef __attribute__((ext_vector_type(8))) short short8;
typedef __attribute__((ext_vector_type(4))) float floatx4;

constexpr int NSPLIT = 16;      // split-K; 512 cols per split

__device__ inline unsigned short f2bf(float f) {
    union { float f; unsigned u; } v; v.f = f;
    unsigned r = v.u + 0x7FFFu + ((v.u >> 16) & 1u);   // RNE
    return (unsigned short)(r >> 16);
}

// ---------- prep: xp = x@wp, Gram partials, Vb = fragment-ordered bf16(x) ----------
__global__ __launch_bounds__(256) void k_prep(const float* __restrict__ x,
                                              const float* __restrict__ wp,
                                              float* __restrict__ xp,
                                              float* __restrict__ Gpart,
                                              unsigned short* __restrict__ Vb) {
    __shared__ float sx[8192];
    __shared__ float swp[1024];
    __shared__ unsigned short st[32][264];
    const int t = threadIdx.x;
    const int n0 = blockIdx.x * 256;
    const floatx4* x4 = (const floatx4*)(x + (size_t)n0 * 32);
    floatx4* sx4 = (floatx4*)sx;
#pragma unroll
    for (int i = 0; i < 8; ++i) sx4[i * 256 + t] = x4[i * 256 + t];
    for (int i = t; i < 1024; i += 256) swp[i] = wp[i];
    __syncthreads();

    float row[32];
#pragma unroll
    for (int a = 0; a < 32; ++a) row[a] = sx[t * 32 + a];

    float* xpr = xp + (size_t)(n0 + t) * 32;
#pragma unroll
    for (int c = 0; c < 32; ++c) {
        float s = 0.f;
#pragma unroll
        for (int a = 0; a < 32; ++a) s += row[a] * swp[a * 32 + c];
        xpr[c] = s;
        st[c][t] = f2bf(row[c]);
    }

    const int a = t >> 3;
    const int b = 4 * (t & 7);
    float g0 = 0.f, g1 = 0.f, g2 = 0.f, g3 = 0.f;
    for (int i = 0; i < 256; ++i) {
        float va = sx[i * 32 + a];
        floatx4 vb = *(floatx4*)&sx[i * 32 + b];
        g0 += va * vb.x; g1 += va * vb.y; g2 += va * vb.z; g3 += va * vb.w;
    }
    floatx4 g = {g0, g1, g2, g3};
    *(floatx4*)&Gpart[(size_t)blockIdx.x * 1024 + (size_t)(a * 32 + b)] = g;

    __syncthreads();
    // emit fragment-ordered B: Vb[kc][h][lane][8], kc = k/32, h = col-half
    const int lane = t & 63, wv = t >> 6;
    const int l15 = lane & 15, l4 = lane >> 4;
    short8* Vb8 = (short8*)Vb;
#pragma unroll
    for (int q = 0; q < 4; ++q) {
        int idx = wv * 4 + q;          // 0..15 -> (c8, h)
        int c8 = idx >> 1, h = idx & 1;
        short8 v = *(const short8*)&st[h * 16 + l15][c8 * 32 + l4 * 8];
        Vb8[((size_t)(n0 / 32 + c8) * 2 + h) * 64 + lane] = v;
    }
}

// ---------- 32x32 coefficient algebra ----------
__global__ void k_coef(const float* __restrict__ Gpart, const float* __restrict__ wp,
                       const float* __restrict__ ts, const float* __restrict__ td,
                       float* __restrict__ Cx, float* __restrict__ Cxp) {
    __shared__ float G[1024], W[1024], H1[1024], H2[1024];
    __shared__ float swp[1024], td1[1024], td2[1024], td3[1024], ts0[1024];
    int t = threadIdx.x;
    int a = t >> 5, b = t & 31;
    float gs = 0.f;
    for (int p = 0; p < 32; ++p) gs += Gpart[p * 1024 + t];
    G[t] = gs; swp[t] = wp[t]; ts0[t] = ts[t];
    td1[t] = td[1024 + t]; td2[t] = td[2048 + t]; td3[t] = td[3072 + t];
    __syncthreads();
    float s = 0.f;
    for (int c = 0; c < 32; ++c) s += G[a * 32 + c] * swp[c * 32 + b];
    W[t] = s; __syncthreads();
    s = 0.f;
    for (int c = 0; c < 32; ++c) s += W[a * 32 + c] * G[c * 32 + b];
    H1[t] = s; __syncthreads();
    s = 0.f;
    for (int c = 0; c < 32; ++c) s += W[a * 32 + c] * H1[c * 32 + b];
    H2[t] = 2.f * s - G[t]; __syncthreads();
    s = 0.f;
    for (int c = 0; c < 32; ++c)
        s += G[a * 32 + c] * td1[c * 32 + b]
           + 2.f * H1[a * 32 + c] * td2[c * 32 + b]
           + (2.f * H2[a * 32 + c] - G[a * 32 + c]) * td3[c * 32 + b];
    Cxp[t] = s;
    Cx[t] = 2.f * ts0[t] - td2[t];
}

// ---------- pass 1: ws(fp32, contiguous 1KB loads) @ V, fused fragment-ordered bf16 emit ----------
// Per-wave private LDS transpose (no barriers); B from fragment-ordered Vb (contiguous).
__global__ __launch_bounds__(256) void k_gemm1(const float* __restrict__ A,
                                               unsigned short* __restrict__ wsb,
                                               const unsigned short* __restrict__ Vb,
                                               float* __restrict__ Ypart) {
    __shared__ unsigned short sbuf[4][16 * 256];   // per-wave 16 rows x 256 bf16
    const int t = threadIdx.x;
    const int lane = t & 63;
    const int wv = t >> 6;
    const int l15 = lane & 15;
    const int l4 = lane >> 4;
    const int bx = blockIdx.x, by = blockIdx.y;
    const int k0 = by * 512;
    const int kc0 = by * 16;                       // global k-chunk base
    const int rowbase = bx * 64 + wv * 16;

    unsigned short* wout =
        wsb + (((size_t)(bx * NSPLIT + by) * 4096) + (size_t)wv * 64 + lane) * 8;
    const short8* Vb8 = (const short8*)Vb;
    unsigned short* mybuf = sbuf[wv];
    const int wchunk = lane >> 1, whalf = lane & 1;

    floatx4 acc0 = {0.f, 0.f, 0.f, 0.f};
    floatx4 acc1 = {0.f, 0.f, 0.f, 0.f};

    for (int s = 0; s < 2; ++s) {
        const int ks = k0 + s * 256;
#pragma unroll
        for (int r = 0; r < 16; ++r) {
            floatx4 f = *(const floatx4*)(A + (size_t)(rowbase + r) * 8192 + ks + lane * 4);
            ushort4 h;
            h.x = f2bf(f.x); h.y = f2bf(f.y); h.z = f2bf(f.z); h.w = f2bf(f.w);
            *(ushort4*)(mybuf + r * 256 + ((wchunk ^ r) * 8 + whalf * 4)) = h;
        }
#pragma unroll 4
        for (int kk = 0; kk < 8; ++kk) {
            short8 av = *(short8*)(mybuf + l15 * 256 + (((kk * 4 + l4) ^ l15) * 8));
            const int kc = kc0 + s * 8 + kk;
            short8 b0 = Vb8[((size_t)kc * 2 + 0) * 64 + lane];
            short8 b1 = Vb8[((size_t)kc * 2 + 1) * 64 + lane];
            *(short8*)(wout + (size_t)(s * 8 + kk) * 2048) = av;
            acc0 = __builtin_amdgcn_mfma_f32_16x16x32_bf16(av, b0, acc0, 0, 0, 0);
            acc1 = __builtin_amdgcn_mfma_f32_16x16x32_bf16(av, b1, acc1, 0, 0, 0);
        }
    }
    float* yp = Ypart + (size_t)by * 262144;
    const int row0 = bx * 64 + wv * 16 + l4 * 4;
#pragma unroll
    for (int r = 0; r < 4; ++r) {
        yp[(size_t)(row0 + r) * 32 + l15] = acc0[r];
        yp[(size_t)(row0 + r) * 32 + 16 + l15] = acc1[r];
    }
}

// ---------- passes 2,3: wsb(frag-ordered) @ Vb(frag-ordered) -> Ypart ----------
// Every load is a contiguous 1KB wave transaction. No LDS, no barriers.
__global__ __launch_bounds__(256) void k_gemm2(const unsigned short* __restrict__ wsb,
                                               const unsigned short* __restrict__ Vb,
                                               float* __restrict__ Ypart) {
    const int t = threadIdx.x;
    const int lane = t & 63;
    const int wv = t >> 6;
    const int l15 = lane & 15;
    const int l4 = lane >> 4;
    const int bx = blockIdx.x, by = blockIdx.y;
    const int kc0 = by * 16;

    const short8* win = (const short8*)wsb
        + ((size_t)(bx * NSPLIT + by) * 4096) + (size_t)wv * 64 + lane;
    const short8* Vb8 = (const short8*)Vb;

    floatx4 acc0 = {0.f, 0.f, 0.f, 0.f};
    floatx4 acc1 = {0.f, 0.f, 0.f, 0.f};

#pragma unroll 4
    for (int c = 0; c < 16; ++c) {
        short8 av = win[(size_t)c * 256];
        short8 b0 = Vb8[((size_t)(kc0 + c) * 2 + 0) * 64 + lane];
        short8 b1 = Vb8[((size_t)(kc0 + c) * 2 + 1) * 64 + lane];
        acc0 = __builtin_amdgcn_mfma_f32_16x16x32_bf16(av, b0, acc0, 0, 0, 0);
        acc1 = __builtin_amdgcn_mfma_f32_16x16x32_bf16(av, b1, acc1, 0, 0, 0);
    }
    float* yp = Ypart + (size_t)by * 262144;
    const int row0 = bx * 64 + wv * 16 + l4 * 4;
#pragma unroll
    for (int r = 0; r < 4; ++r) {
        yp[(size_t)(row0 + r) * 32 + l15] = acc0[r];
        yp[(size_t)(row0 + r) * 32 + 16 + l15] = acc1[r];
    }
}

// ---------- reduce split-K partials + alpha/beta + emit y and fragment-ordered Vb ----------
__global__ __launch_bounds__(256) void k_trans(const float* __restrict__ Ypart,
                                               const float* __restrict__ prev,
                                               float alpha, float beta,
                                               float* __restrict__ y,
                                               unsigned short* __restrict__ Vb) {
    __shared__ unsigned short st[32][264];
    const int t = threadIdx.x;
    const int n0 = blockIdx.x * 256;
    const size_t base4 = (size_t)n0 * 8;
    floatx4 r[8];
#pragma unroll
    for (int j = 0; j < 8; ++j) r[j] = {0.f, 0.f, 0.f, 0.f};
    for (int p = 0; p < NSPLIT; ++p) {
        const floatx4* P4 = (const floatx4*)(Ypart + (size_t)p * 262144);
#pragma unroll
        for (int j = 0; j < 8; ++j) r[j] += P4[base4 + j * 256 + t];
    }
    const floatx4* prev4 = (const floatx4*)prev;
    floatx4* y4 = (floatx4*)y;
#pragma unroll
    for (int j = 0; j < 8; ++j) {
        floatx4 pv = prev4[base4 + j * 256 + t];
        floatx4 v;
        v.x = alpha * r[j].x + beta * pv.x;
        v.y = alpha * r[j].y + beta * pv.y;
        v.z = alpha * r[j].z + beta * pv.z;
        v.w = alpha * r[j].w + beta * pv.w;
        y4[base4 + j * 256 + t] = v;
        int q = j * 256 + t;
        int lr = q >> 3;
        int c4 = (q & 7) * 4;
        st[c4 + 0][lr] = f2bf(v.x);
        st[c4 + 1][lr] = f2bf(v.y);
        st[c4 + 2][lr] = f2bf(v.z);
        st[c4 + 3][lr] = f2bf(v.w);
    }
    __syncthreads();
    const int lane = t & 63, wv = t >> 6;
    const int l15 = lane & 15, l4 = lane >> 4;
    short8* Vb8 = (short8*)Vb;
#pragma unroll
    for (int q = 0; q < 4; ++q) {
        int idx = wv * 4 + q;
        int c8 = idx >> 1, h = idx & 1;
        short8 v = *(const short8*)&st[h * 16 + l15][c8 * 32 + l4 * 8];
        Vb8[((size_t)(n0 / 32 + c8) * 2 + h) * 64 + lane] = v;
    }
}

// ---------- out = x@Cx + xp@Cxp + y1@ts1 + y2@ts2 + y3@ts3 ----------
__global__ void k_final(const float* __restrict__ x, const float* __restrict__ xp,
                        const float* __restrict__ y1, const float* __restrict__ y2,
                        const float* __restrict__ y3, const float* __restrict__ Cx,
                        const float* __restrict__ Cxp, const float* __restrict__ ts,
                        float* __restrict__ out) {
    __shared__ float m0[1024], m1[1024], m2[1024], m3[1024], m4[1024];
    int t = threadIdx.x;
    for (int i = t; i < 1024; i += 256) {
        m0[i] = Cx[i]; m1[i] = Cxp[i];
        m2[i] = ts[1024 + i]; m3[i] = ts[2048 + i]; m4[i] = ts[3072 + i];
    }
    __syncthreads();
    int g = blockIdx.x * 256 + t;
    int n = g >> 5, c = g & 31;
    const float* xr  = x  + (size_t)n * 32;
    const float* xpr = xp + (size_t)n * 32;
    const float* y1r = y1 + (size_t)n * 32;
    const float* y2r = y2 + (size_t)n * 32;
    const float* y3r = y3 + (size_t)n * 32;
    float s = 0.f;
#pragma unroll
    for (int a = 0; a < 32; ++a) {
        s += xr[a]  * m0[a * 32 + c]
           + xpr[a] * m1[a * 32 + c]
           + y1r[a] * m2[a * 32 + c]
           + y2r[a] * m3[a * 32 + c]
           + y3r[a] * m4[a * 32 + c];
    }
    out[g] = s;
}

extern "C" void kernel_launch(void* const* d_in, const int* in_sizes, int n_in,
                              void* d_out, int out_size, void* d_ws, size_t ws_size,
                              hipStream_t stream) {
    const float* x  = (const float*)d_in[0];   // 8192 x 32
    const float* ws = (const float*)d_in[1];   // 8192 x 8192
    const float* wp = (const float*)d_in[2];   // 32 x 32
    const float* ts = (const float*)d_in[3];   // 4 x 32 x 32
    const float* td = (const float*)d_in[4];   // 4 x 32 x 32
    float* out = (float*)d_out;

    char* w = (char*)d_ws;
    unsigned short* wsb = (unsigned short*)w;              // 128 MB, fragment-ordered bf16
    float* Ppart = (float*)(w + 134217728);                // NSPLIT x 8192 x 32 (16 MB)
    float* xp  = Ppart + (size_t)NSPLIT * 262144;
    float* y1  = xp + 262144;
    float* y2  = y1 + 262144;
    float* y3  = y2 + 262144;
    unsigned short* Vb = (unsigned short*)(y3 + 262144);   // 512 KB fragment-ordered B
    float* Gpart = (float*)(Vb + 262144);                  // 32 x 1024
    float* Cx  = Gpart + 32768;
    float* Cxp = Cx + 1024;

    dim3 gg(128, NSPLIT);
    k_prep<<<32, 256, 0, stream>>>(x, wp, xp, Gpart, Vb);
    k_coef<<<1, 1024, 0, stream>>>(Gpart, wp, ts, td, Cx, Cxp);
    // pass 1: y1 = ws @ x   (+ fused fragment-ordered bf16 emit)
    k_gemm1<<<gg, 256, 0, stream>>>(ws, wsb, Vb, Ppart);
    k_trans<<<32, 256, 0, stream>>>(Ppart, x, 1.0f, 0.0f, y1, Vb);
    // pass 2: y2 = 2 ws @ y1 - x
    k_gemm2<<<gg, 256, 0, stream>>>(wsb, Vb, Ppart);
    k_trans<<<32, 256, 0, stream>>>(Ppart, x, 2.0f, -1.0f, y2, Vb);
    // pass 3: y3 = 2 ws @ y2 - y1
    k_gemm2<<<gg, 256, 0, stream>>>(wsb, Vb, Ppart);
    k_trans<<<32, 256, 0, stream>>>(Ppart, y1, 2.0f, -1.0f, y3, Vb);

    k_final<<<1024, 256, 0, stream>>>(x, xp, y1, y2, y3, Cx, Cxp, ts, out);
}